// Round 5
// baseline (469.658 us; speedup 1.0000x reference)
//
#include <hip/hip_runtime.h>
#include <hip/hip_bf16.h>
#include <stdint.h>

// Problem constants (from reference)
#define M_DIM 8192              // 4*2048 batch*seq rows
#define N_DIM 4096              // out_features
#define K_DIM 4096              // in_features
#define NOG   4096              // num out groups (out_group=1)
#define NIG   512               // num in groups (in_group=8)

typedef __bf16 bf16;
typedef __attribute__((ext_vector_type(8))) __bf16 bf16x8;   // 4 VGPRs — MFMA A/B frag
typedef __attribute__((ext_vector_type(4))) float f32x4;     // MFMA C/D frag

// Tiled bf16 layout for both GEMM operands ("chunk order"):
//   tile(g, h) = rows [g*16,(g+1)*16) x cols [h*32,(h+1)*32)
//   stored as 64 consecutive 16-B chunks, chunk index c = kblk*16 + row
//   (kblk = 8-elem block within the 32 cols, row = row within group).
//   global chunk id = (g * 128 + h) * 64 + kblk * 16 + row.
// GEMM staging then reads 1024 CONTIGUOUS bytes per gload16 (lane l -> chunk l)
// and LDS receives fragment-read order -> zero bank conflicts (measured 0).

// ---------------------------------------------------------------------------
// async global->LDS, 16 B per lane. LDS dest is wave-uniform base + lane*16.
__device__ __forceinline__ void gload16(const void* g, void* lds) {
    __builtin_amdgcn_global_load_lds(
        (__attribute__((address_space(1))) void*)g,
        (__attribute__((address_space(3))) void*)lds,
        16 /*size*/, 0 /*offset*/, 0 /*aux*/);
}

// ---------------------------------------------------------------------------
// Kernel 1: fp32 -> bf16 convert + transpose into chunk-order tiles.
// REWRITTEN as a no-LDS grid-stride streamer: one thread produces one 16-B
// output chunk from 32 CONTIGUOUS input bytes. Decode of chunk id:
//   r = id&15, kblk = (id>>4)&3, h = (id>>6)&127, g = id>>13
//   input addr = (g*16 + r)*K_DIM + h*32 + kblk*8   (8 consecutive floats)
// A wave's 64 chunks read 16 rows x 128 contiguous bytes -> full cache-line
// utilization; stores are perfectly coalesced (consecutive id). No barriers,
// no LDS -> latency hidden purely by occupancy (8 waves/CU, trivial VGPR).
__global__ __launch_bounds__(256) void k_convert(const float* __restrict__ in,
                                                 bf16* __restrict__ out) {
    const int total  = M_DIM * (K_DIM / 8);              // 4,194,304 chunks
    const int stride = gridDim.x * 256;
    for (int id = blockIdx.x * 256 + threadIdx.x; id < total; id += stride) {
        const int r    = id & 15;
        const int kblk = (id >> 4) & 3;
        const int h    = (id >> 6) & 127;
        const int g    = id >> 13;
        const float4* p = (const float4*)(in + (size_t)(g * 16 + r) * K_DIM
                                             + h * 32 + kblk * 8);
        float4 a = p[0], b = p[1];
        bf16x8 v;
        v[0] = (bf16)a.x; v[1] = (bf16)a.y; v[2] = (bf16)a.z; v[3] = (bf16)a.w;
        v[4] = (bf16)b.x; v[5] = (bf16)b.y; v[6] = (bf16)b.z; v[7] = (bf16)b.w;
        ((bf16x8*)out)[id] = v;
    }
}

// ---------------------------------------------------------------------------
// Kernel 2: AQLM dequant into chunk-order tiles. Same grid-stride chunk
// mapping: out-feature o = g*16 + r, in-group iG = h*4 + kblk. Per chunk:
// one 4-B code, one 4-B scale, one 32-B codebook gather (2 MB table ->
// L2-resident), one coalesced 16-B store. A block's code reads per g land
// on one 64-B line per out-feature row.
__global__ __launch_bounds__(256) void k_dequant(const int* __restrict__ codes,
                                                 const float* __restrict__ cb,
                                                 const float* __restrict__ scales,
                                                 bf16* __restrict__ w) {
    const int total  = NOG * (K_DIM / 8);                // 2,097,152 chunks
    const int stride = gridDim.x * 256;
    for (int id = blockIdx.x * 256 + threadIdx.x; id < total; id += stride) {
        const int r    = id & 15;
        const int kblk = (id >> 4) & 3;
        const int h    = (id >> 6) & 127;
        const int g    = id >> 13;
        const int o    = g * 16 + r;
        const int iG   = h * 4 + kblk;
        const unsigned code = (unsigned)codes[o * NIG + iG];
        const float s = scales[o];
        const float4* e = (const float4*)(cb + (size_t)code * 8);
        float4 e0 = e[0], e1 = e[1];
        bf16x8 v;
        v[0] = (bf16)(e0.x * s); v[1] = (bf16)(e0.y * s);
        v[2] = (bf16)(e0.z * s); v[3] = (bf16)(e0.w * s);
        v[4] = (bf16)(e1.x * s); v[5] = (bf16)(e1.y * s);
        v[6] = (bf16)(e1.z * s); v[7] = (bf16)(e1.w * s);
        ((bf16x8*)w)[id] = v;
    }
}

// ---------------------------------------------------------------------------
// Kernel 3: C[m,n] = sum_k A[m,k]*B[n,k] + bias[n]  on chunk-order tiles.
// VERBATIM round-0 version (measured 239.8 us, MfmaUtil 50.5) — the proven
// best. 48 KB LDS -> ~2 blocks/CU co-resident; inter-block asynchrony
// overlaps one block's LDS-read burst with another's MFMA burst (m114
// implicit overlap). All deeper-pipelined 1-block/CU variants measured
// SLOWER (rounds 2-4: 245.7 / 281.5 / 260.8) — do not re-attempt without a
// mechanism for cross-block-style overlap.
#define BM 256
#define BN 128
#define BK 64
#define KSTEPS (K_DIM / BK)

__global__ __launch_bounds__(256, 2) void k_gemm_tiled(
    const bf16* __restrict__ A,      // chunk-order tiled [512 groups][128 halves]
    const bf16* __restrict__ B,      // chunk-order tiled [256 groups][128 halves]
    const float* __restrict__ bias,  // [N_DIM]
    float* __restrict__ C)           // [M_DIM, N_DIM] row-major
{
    // LDS: per group-half 512 elems (64 chunks); As = 16 groups x 2 halves.
    __shared__ __align__(16) bf16 As[BM * BK];   // 32 KB
    __shared__ __align__(16) bf16 Bs[BN * BK];   // 16 KB

    const int tid  = threadIdx.x;
    const int wave = tid >> 6;         // 0..3
    const int lane = tid & 63;
    const int quad = lane >> 4;        // 0..3
    const int l16  = lane & 15;

    const int bn0 = blockIdx.x * BN;
    const int bm0 = blockIdx.y * BM;
    const int wm = (wave >> 1) * 128;  // wave's 128x64 subtile
    const int wn = (wave & 1) * 64;

    // Staging sources: lane l fetches chunk l of each group-half tile.
    // Group stride in chunks = 128 halves * 64 = 8192; elems = *8.
    const bf16* pA[4];
    const bf16* pB[2];
    #pragma unroll
    for (int gi = 0; gi < 4; ++gi) {
        const int g = blockIdx.y * 16 + wave * 4 + gi;     // A group
        pA[gi] = A + ((size_t)g * 8192 + lane) * 8;
    }
    #pragma unroll
    for (int gi = 0; gi < 2; ++gi) {
        const int g = blockIdx.x * 8 + wave * 2 + gi;      // B group
        pB[gi] = B + ((size_t)g * 8192 + lane) * 8;
    }
    bf16* AsW = As + wave * 4096;      // wave's 4 A-groups (4*2*512)
    bf16* BsW = Bs + wave * 2048;      // wave's 2 B-groups

    const int gA0 = (wave >> 1) * 8;   // first A group this wave reads
    const int gB0 = (wave & 1) * 4;    // first B group

    f32x4 acc[8][4] = {};

    for (int ks = 0; ks < KSTEPS; ++ks) {
        #pragma unroll
        for (int gi = 0; gi < 4; ++gi) {
            gload16(pA[gi],       AsW + gi * 1024);        // half 0: 1024 B contig
            gload16(pA[gi] + 512, AsW + gi * 1024 + 512);  // half 1
            pA[gi] += 1024;                                 // advance 2 halves
        }
        #pragma unroll
        for (int gi = 0; gi < 2; ++gi) {
            gload16(pB[gi],       BsW + gi * 1024);
            gload16(pB[gi] + 512, BsW + gi * 1024 + 512);
            pB[gi] += 1024;
        }
        __syncthreads();   // drains vmcnt -> staged data visible

        // Fragment reads: 64 consecutive chunks per read -> conflict-free.
        // Lane's elems: A[m = l16][k = quad*8..+8] of (group, half).
        bf16x8 af0[8], af1[8], bq0[4], bq1[4];
        #pragma unroll
        for (int t = 0; t < 8; ++t) {
            af0[t] = *(const bf16x8*)(As + (size_t)(gA0 + t) * 1024 + lane * 8);
            af1[t] = *(const bf16x8*)(As + (size_t)(gA0 + t) * 1024 + 512 + lane * 8);
        }
        #pragma unroll
        for (int t = 0; t < 4; ++t) {
            bq0[t] = *(const bf16x8*)(Bs + (size_t)(gB0 + t) * 1024 + lane * 8);
            bq1[t] = *(const bf16x8*)(Bs + (size_t)(gB0 + t) * 1024 + 512 + lane * 8);
        }

        #pragma unroll
        for (int i = 0; i < 8; ++i)
            #pragma unroll
            for (int j = 0; j < 4; ++j)
                acc[i][j] = __builtin_amdgcn_mfma_f32_16x16x32_bf16(
                    af0[i], bq0[j], acc[i][j], 0, 0, 0);
        #pragma unroll
        for (int i = 0; i < 8; ++i)
            #pragma unroll
            for (int j = 0; j < 4; ++j)
                acc[i][j] = __builtin_amdgcn_mfma_f32_16x16x32_bf16(
                    af1[i], bq1[j], acc[i][j], 0, 0, 0);

        __syncthreads();   // all reads done before next overwrite
    }

    // Epilogue: C/D layout col = lane&15, row = quad*4 + reg  [m89/m91-verified]
    #pragma unroll
    for (int j = 0; j < 4; ++j) {
        const int gn = bn0 + wn + j * 16 + l16;
        const float bz = bias[gn];
        #pragma unroll
        for (int i = 0; i < 8; ++i) {
            float* cp = C + (size_t)(bm0 + wm + i * 16 + quad * 4) * N_DIM + gn;
            #pragma unroll
            for (int r = 0; r < 4; ++r)
                cp[(size_t)r * N_DIM] = acc[i][j][r] + bz;
        }
    }
}

// ---------------------------------------------------------------------------
extern "C" void kernel_launch(void* const* d_in, const int* in_sizes, int n_in,
                              void* d_out, int out_size, void* d_ws, size_t ws_size,
                              hipStream_t stream) {
    const float* input     = (const float*)d_in[0];   // [4,2048,4096]
    const int*   codes     = (const int*)d_in[1];     // [4096,512,1]
    const float* codebooks = (const float*)d_in[2];   // [1,65536,1,8]
    const float* scales    = (const float*)d_in[3];   // [4096]
    const float* bias      = (const float*)d_in[4];   // [4096]
    float* out = (float*)d_out;                        // [4,2048,4096]

    // Workspace: A_tiled (67.1 MB) then W_tiled (33.5 MB); both fully written
    // before the GEMM reads them, so the 0xAA poison is irrelevant.
    bf16* Abf = (bf16*)d_ws;
    bf16* Wbf = (bf16*)((char*)d_ws + (size_t)M_DIM * K_DIM * sizeof(bf16));

    (void)in_sizes; (void)n_in; (void)out_size; (void)ws_size;

    // 1) activation fp32 -> bf16, tiled. Grid-stride streamer:
    //    2048 blocks x 256 thr (8 waves/CU), 8 chunks/thread.
    k_convert<<<dim3(2048), 256, 0, stream>>>(input, Abf);

    // 2) dequantize W -> bf16, tiled. 2048 blocks, 4 chunks/thread.
    k_dequant<<<dim3(2048), 256, 0, stream>>>(codes, codebooks, scales, Wbf);

    // 3) NT GEMM + bias on tiled operands (round-0 proven kernel).
    {
        dim3 g(N_DIM / BN, M_DIM / BM);   // (32, 32)
        k_gemm_tiled<<<g, 256, 0, stream>>>(Abf, Wbf, bias, out);
    }
}